// Round 2
// baseline (6579.449 us; speedup 1.0000x reference)
//
#include <hip/hip_runtime.h>
#include <hip/hip_bf16.h>

typedef unsigned short u16;
typedef unsigned int u32;

__device__ __forceinline__ float bf2f(u16 u) {
  u32 x = ((u32)u) << 16;
  union { u32 i; float f; } c; c.i = x; return c.f;
}
__device__ __forceinline__ float lrelu(float x) { return x > 0.f ? x : 0.2f * x; }

// float atomic max via sign-split (init must be -inf)
__device__ __forceinline__ void atomicMaxF(float* addr, float val) {
  if (val >= 0.f) atomicMax((int*)addr, __float_as_int(val));
  else            atomicMin((u32*)addr, __float_as_uint(val));
}

// stage n elements from global (bf16-or-f32 per mode) into LDS as f32
__device__ __forceinline__ void stage(float* dst, const void* src, int n, int mode) {
  if (mode) {
    const u16* s = (const u16*)src;
    for (int i = threadIdx.x; i < n; i += blockDim.x) dst[i] = bf2f(s[i]);
  } else {
    const float* s = (const float*)src;
    for (int i = threadIdx.x; i < n; i += blockDim.x) dst[i] = s[i];
  }
}

__device__ __forceinline__ float loadIn(const void* p, long long i, int mode) {
  return mode ? bf2f(((const u16*)p)[i]) : ((const float*)p)[i];
}

// init ws + detect dtype. If Wm1 is f32, its even u16 halves are random bits
// (garbage exponents); if bf16, all |w| < 0.084. mode: 1 = bf16, 0 = f32.
__global__ void detect_init(const void* Wm1p, float* __restrict__ nf1,
                            float* __restrict__ nf2, int n32, int* __restrict__ modep) {
  int tid = blockIdx.x * blockDim.x + threadIdx.x;
  for (int i = tid; i < n32; i += gridDim.x * blockDim.x) {
    nf1[i] = 0.f; nf2[i] = -__builtin_inff();
  }
  if (blockIdx.x == 0) {
    __shared__ int flag;
    if (threadIdx.x == 0) flag = 0;
    __syncthreads();
    const u16* w = (const u16*)Wm1p;
    int bad = 0;
    for (int i = threadIdx.x; i < 4608; i += blockDim.x) {
      float v = bf2f(w[2 * i]);
      if (!(v > -1.f && v < 1.f)) bad = 1;   // catches NaN too
    }
    if (bad) flag = 1;                        // benign race, all write 1
    __syncthreads();
    if (threadIdx.x == 0) *modep = (flag ? 0 : 1);
  }
}

// -------- edge kernel: wave-per-edge, 16 waves / 1024-thread block --------
// dyn LDS floats: W[29760] | B[321] | xbuf[16*160] | hbuf[16*128]  = 138756 B
__global__ __launch_bounds__(1024) void edge_kernel(
    const void* __restrict__ nf, const void* __restrict__ ef,
    const int* __restrict__ src, const int* __restrict__ dst,
    const void* Wm1, const void* bm1, const void* Wm2, const void* bm2,
    const void* Wm3, const void* bm3, const void* Wm4, const void* bm4,
    float* __restrict__ nf1, float* __restrict__ nf2,
    const int* __restrict__ modep, int E)
{
  extern __shared__ float smem[];
  float* Wf = smem;                 // W1[144x64]@0 W2[64x128]@9216 W3[128x64]@17408 W4[64x65]@25600
  float* Bf = smem + 29760;         // b1@0 b2@64 b3@192 b4@256 (321)
  float* xb_all = smem + 30081;     // 16 x 160
  float* hb_all = smem + 32641;     // 16 x 128

  const int mode = *modep;

  stage(Wf,          Wm1, 9216, mode);
  stage(Wf + 9216,   Wm2, 8192, mode);
  stage(Wf + 17408,  Wm3, 8192, mode);
  stage(Wf + 25600,  Wm4, 4160, mode);
  stage(Bf,          bm1, 64,   mode);
  stage(Bf + 64,     bm2, 128,  mode);
  stage(Bf + 192,    bm3, 64,   mode);
  stage(Bf + 256,    bm4, 65,   mode);
  __syncthreads();

  const int lane = threadIdx.x & 63;
  const int wv   = threadIdx.x >> 6;
  float* xb = xb_all + wv * 160;
  float* hb = hb_all + wv * 128;

  for (long long base = (long long)blockIdx.x * 16; base < E; base += (long long)gridDim.x * 16) {
    const long long e = base + wv;
    const bool act = (e < E);
    int s = 0, d = 0;
    if (act) { s = src[e]; d = dst[e]; }

    // stage x = [nf[src](64) | nf[dst](64) | ef(16)]
    if (act) {
      for (int i = lane; i < 144; i += 64) {
        float v;
        if (i < 64)       v = loadIn(nf, (long long)s * 64 + i, mode);
        else if (i < 128) v = loadIn(nf, (long long)d * 64 + (i - 64), mode);
        else              v = loadIn(ef, e * 16 + (i - 128), mode);
        xb[i] = v;
      }
    }
    __syncthreads();

    // L1: 144 -> 64 (lrelu)
    if (act) {
      float acc = Bf[lane];
      #pragma unroll 8
      for (int k = 0; k < 144; ++k) acc += xb[k] * Wf[k * 64 + lane];
      hb[lane] = lrelu(acc);
    }
    __syncthreads();

    // L2: 64 -> 128 (lrelu), outputs into xbuf (x is dead)
    if (act) {
      float a0 = Bf[64 + lane], a1 = Bf[128 + lane];
      #pragma unroll 8
      for (int k = 0; k < 64; ++k) {
        float x = hb[k];
        a0 += x * Wf[9216 + k * 128 + lane];
        a1 += x * Wf[9216 + k * 128 + 64 + lane];
      }
      xb[lane]      = lrelu(a0);
      xb[64 + lane] = lrelu(a1);
    }
    __syncthreads();

    // L3: 128 -> 64 (lrelu)
    if (act) {
      float acc = Bf[192 + lane];
      #pragma unroll 8
      for (int k = 0; k < 128; ++k) acc += xb[k] * Wf[17408 + k * 64 + lane];
      hb[lane] = lrelu(acc);
    }
    __syncthreads();

    // L4: 64 -> 65 (linear). gate = col 0 (broadcast); lane j -> col j+1
    if (act) {
      float g = Bf[256];
      float f = Bf[257 + lane];
      #pragma unroll 8
      for (int k = 0; k < 64; ++k) {
        float x = hb[k];
        g += x * Wf[25600 + k * 65];
        f += x * Wf[25600 + k * 65 + 1 + lane];
      }
      float kg  = 1.f / (1.f + __expf(-g));
      float val = f * kg;
      if (lane < 32) atomicAdd(&nf1[(long long)d * 32 + lane], val);
      else           atomicMaxF(&nf2[(long long)d * 32 + (lane - 32)], val);
    }
    __syncthreads();
  }
}

// -------- node kernel: wave-per-node, 16 waves / 1024-thread block --------
// dyn LDS floats: W[28672] | B[320] | ybuf[16*128] | hbuf[16*128] = 132352 B
__global__ __launch_bounds__(1024) void node_kernel(
    const void* __restrict__ nf,
    const float* __restrict__ nf1, const float* __restrict__ nf2,
    const void* Wr1, const void* br1, const void* Wr2, const void* br2,
    const void* Wr3, const void* br3, const void* Wr4, const void* br4,
    void* __restrict__ outp, const int* __restrict__ modep, int N)
{
  extern __shared__ float smem[];
  float* Wf = smem;                 // W1[128x64]@0 W2[64x128]@8192 W3[128x64]@16384 W4[64x64]@24576
  float* Bf = smem + 28672;         // 320
  float* yb_all = smem + 28992;     // 16 x 128
  float* hb_all = smem + 31040;     // 16 x 128

  const int mode = *modep;

  stage(Wf,          Wr1, 8192, mode);
  stage(Wf + 8192,   Wr2, 8192, mode);
  stage(Wf + 16384,  Wr3, 8192, mode);
  stage(Wf + 24576,  Wr4, 4096, mode);
  stage(Bf,          br1, 64,  mode);
  stage(Bf + 64,     br2, 128, mode);
  stage(Bf + 192,    br3, 64,  mode);
  stage(Bf + 256,    br4, 64,  mode);
  __syncthreads();

  const int lane = threadIdx.x & 63;
  const int wv   = threadIdx.x >> 6;
  float* yb = yb_all + wv * 128;
  float* hb = hb_all + wv * 128;

  for (long long base = (long long)blockIdx.x * 16; base < N; base += (long long)gridDim.x * 16) {
    const long long n = base + wv;
    const bool act = (n < N);

    if (act) {
      yb[lane] = loadIn(nf, n * 64 + lane, mode);
      int i = lane + 64;
      if (i < 96) {
        yb[i] = nf1[n * 32 + (i - 64)];
      } else {
        float v = nf2[n * 32 + (i - 96)];
        if (!(v >= -3.0e38f && v <= 3.0e38f)) v = 0.f;  // -inf (no in-edges) -> 0
        yb[i] = v;
      }
    }
    __syncthreads();

    if (act) {
      float acc = Bf[lane];
      #pragma unroll 8
      for (int k = 0; k < 128; ++k) acc += yb[k] * Wf[k * 64 + lane];
      hb[lane] = lrelu(acc);
    }
    __syncthreads();

    if (act) {
      float a0 = Bf[64 + lane], a1 = Bf[128 + lane];
      #pragma unroll 8
      for (int k = 0; k < 64; ++k) {
        float x = hb[k];
        a0 += x * Wf[8192 + k * 128 + lane];
        a1 += x * Wf[8192 + k * 128 + 64 + lane];
      }
      yb[lane]      = lrelu(a0);
      yb[64 + lane] = lrelu(a1);
    }
    __syncthreads();

    if (act) {
      float acc = Bf[192 + lane];
      #pragma unroll 8
      for (int k = 0; k < 128; ++k) acc += yb[k] * Wf[16384 + k * 64 + lane];
      hb[lane] = lrelu(acc);
    }
    __syncthreads();

    if (act) {
      float acc = Bf[256 + lane];
      #pragma unroll 8
      for (int k = 0; k < 64; ++k) acc += hb[k] * Wf[24576 + k * 64 + lane];
      if (mode) ((__hip_bfloat16*)outp)[n * 64 + lane] = __float2bfloat16(acc);
      else      ((float*)outp)[n * 64 + lane] = acc;
    }
    __syncthreads();
  }
}

extern "C" void kernel_launch(void* const* d_in, const int* in_sizes, int n_in,
                              void* d_out, int out_size, void* d_ws, size_t ws_size,
                              hipStream_t stream) {
  const void* nf  = d_in[0];
  const void* ef  = d_in[1];
  const int* src = (const int*)d_in[2];
  const int* dst = (const int*)d_in[3];

  const int N = in_sizes[0] / 64;
  const int E = in_sizes[2];

  float* nf1 = (float*)d_ws;               // [N,32] segment-sum
  float* nf2 = nf1 + (size_t)N * 32;       // [N,32] segment-max
  int* modep = (int*)(nf2 + (size_t)N * 32);

  const int n32 = N * 32;
  detect_init<<<4096, 256, 0, stream>>>(d_in[4], nf1, nf2, n32, modep);

  const int edge_lds = 34689 * 4;   // 138756 B
  const int node_lds = 33088 * 4;   // 132352 B
  hipFuncSetAttribute((const void*)edge_kernel, hipFuncAttributeMaxDynamicSharedMemorySize, edge_lds);
  hipFuncSetAttribute((const void*)node_kernel, hipFuncAttributeMaxDynamicSharedMemorySize, node_lds);

  edge_kernel<<<256, 1024, edge_lds, stream>>>(
      nf, ef, src, dst,
      d_in[4], d_in[5], d_in[6], d_in[7],
      d_in[8], d_in[9], d_in[10], d_in[11],
      nf1, nf2, modep, E);

  node_kernel<<<256, 1024, node_lds, stream>>>(
      nf, nf1, nf2,
      d_in[12], d_in[13], d_in[14], d_in[15],
      d_in[16], d_in[17], d_in[18], d_in[19],
      d_out, modep, N);
}

// Round 6
// 1365.970 us; speedup vs baseline: 4.8167x; 4.8167x over previous
//
#include <hip/hip_runtime.h>

typedef unsigned int u32;
typedef __attribute__((ext_vector_type(8))) short short8;
typedef __attribute__((ext_vector_type(4))) float f32x4;

__device__ __forceinline__ float lrelu(float x){ return x > 0.f ? x : 0.2f*x; }

// float atomic max via sign-split (dest init -inf)
__device__ __forceinline__ void atomicMaxF(float* a, float v){
  if (__float_as_int(v) >= 0) atomicMax((int*)a, __float_as_int(v));
  else                        atomicMin((u32*)a, __float_as_uint(v));
}

__global__ void init_ws(float* __restrict__ nf1, float* __restrict__ nf2, int n32){
  int i = blockIdx.x*blockDim.x + threadIdx.x;
  int st = gridDim.x*blockDim.x;
  for (; i < n32; i += st){ nf1[i] = 0.f; nf2[i] = -__builtin_inff(); }
}

// RNE split: x = bf16(hi) + bf16(lo) + O(2^-18 x). Returns (hi, lo) packed.
struct HL { short hi, lo; };
__device__ __forceinline__ HL split1(float x){
  u32 u = __float_as_uint(x);
  u32 r = u + 0x7FFFu + ((u >> 16) & 1u);
  float l = x - __uint_as_float(r & 0xFFFF0000u);
  HL o; o.hi = (short)(r >> 16); o.lo = (short)(__float_as_uint(l) >> 16);
  return o;
}

// A-chunk (8 f32 from LDS row) -> hi/lo bf16 fragments
__device__ __forceinline__ void splitA(const float* arow, int k0, short8& hi, short8& lo){
  f32x4 x0 = *(const f32x4*)(arow + k0);
  f32x4 x1 = *(const f32x4*)(arow + k0 + 4);
  #pragma unroll
  for (int j = 0; j < 4; ++j){
    HL a = split1(x0[j]); hi[j]   = a.hi; lo[j]   = a.lo;
    HL b = split1(x1[j]); hi[4+j] = b.hi; lo[4+j] = b.lo;
  }
}

// one-time gather of a B fragment (W row-major [K][Nout], f32) with zero-fill OOB
__device__ __forceinline__ void gatherB(const float* __restrict__ W, int K, int Nout,
                                        int kbase, int n, short8& hi, short8& lo){
  #pragma unroll
  for (int j = 0; j < 8; ++j){
    int k = kbase + j;
    float w = (k < K && n < Nout) ? W[(size_t)k * Nout + n] : 0.f;
    HL s = split1(w); hi[j] = s.hi; lo[j] = s.lo;
  }
}

// 3-product accurate bf16 MFMA: D += Ah*Bh + Al*Bh + Ah*Bl
__device__ __forceinline__ f32x4 mfma3(short8 ah, short8 al, short8 bh, short8 bl, f32x4 c){
  c = __builtin_amdgcn_mfma_f32_16x16x32_bf16(ah, bh, c, 0, 0, 0);
  c = __builtin_amdgcn_mfma_f32_16x16x32_bf16(al, bh, c, 0, 0, 0);
  c = __builtin_amdgcn_mfma_f32_16x16x32_bf16(ah, bl, c, 0, 0, 0);
  return c;
}

__device__ void zero_f(float* p, int n){
  for (int i = threadIdx.x; i < n; i += blockDim.x) p[i] = 0.f;
}

#define B0S 164   // edge buf0 stride (f32): 164%32=4 -> 2-way banks (free); 656B %16=0
#define B1S 68    // h-buffer stride: 68%32=4 -> 2-way; 272B %16=0

// -------- edge kernel: 32 edges per block-tile, 8 waves, weights in VGPRs --------
// MLP_msg 144->64->128->64->65; gate=sigmoid(col0); cols1..32 *g -> sum, 33..64 *g -> max
__global__ __launch_bounds__(512, 2) void edge_mfma(
    const float* __restrict__ nf, const float* __restrict__ ef,
    const int* __restrict__ src, const int* __restrict__ dst,
    const float* __restrict__ Wm1, const float* __restrict__ bm1,
    const float* __restrict__ Wm2, const float* __restrict__ bm2,
    const float* __restrict__ Wm3, const float* __restrict__ bm3,
    const float* __restrict__ Wm4, const float* __restrict__ bm4,
    float* __restrict__ nf1, float* __restrict__ nf2, int E)
{
  __shared__ float buf0[32*B0S];   // X (160 cols) then h2 (128 cols)
  __shared__ float buf1[32*B1S];   // h1 / h3 (64 cols)
  __shared__ int   dstIds[32];
  __shared__ float gates[32];

  zero_f(buf0, 32*B0S);            // uninit LDS can hold NaN patterns; 0*NaN = NaN in MFMA
  zero_f(buf1, 32*B1S);

  const int lane = threadIdx.x & 63, wv = threadIdx.x >> 6;
  const int nl = lane & 15, quad = lane >> 4;
  const int m1 = wv >> 2, nb1 = wv & 3;   // this wave's (m-block, n-block)

  // ---- cache all B fragments (hi/lo bf16) in registers; loop-invariant ----
  short8 B1h[5], B1l[5];
  #pragma unroll
  for (int kc = 0; kc < 5; ++kc) gatherB(Wm1, 144, 64,  kc*32 + quad*8, nb1*16 + nl, B1h[kc], B1l[kc]);
  short8 B2h[2][2], B2l[2][2];
  #pragma unroll
  for (int i = 0; i < 2; ++i)
    #pragma unroll
    for (int kc = 0; kc < 2; ++kc) gatherB(Wm2, 64, 128, kc*32 + quad*8, (nb1 + i*4)*16 + nl, B2h[i][kc], B2l[i][kc]);
  short8 B3h[4], B3l[4];
  #pragma unroll
  for (int kc = 0; kc < 4; ++kc) gatherB(Wm3, 128, 64,  kc*32 + quad*8, nb1*16 + nl, B3h[kc], B3l[kc]);
  short8 B4h[2][2], B4l[2][2];     // tileA: nb1 ; tileB: col 64 (gate-extra col, only col64 real)
  #pragma unroll
  for (int kc = 0; kc < 2; ++kc){
    gatherB(Wm4, 64, 65, kc*32 + quad*8, nb1*16 + nl, B4h[0][kc], B4l[0][kc]);
    gatherB(Wm4, 64, 65, kc*32 + quad*8, 64 + nl,     B4h[1][kc], B4l[1][kc]);
  }
  const float bi1  = bm1[nb1*16 + nl];
  const float bi2a = bm2[nb1*16 + nl], bi2b = bm2[(nb1+4)*16 + nl];
  const float bi3  = bm3[nb1*16 + nl];
  const float bi4a = bm4[nb1*16 + nl];                  // nb1*16+nl <= 63 < 65 ok
  const float bi4b = (nl == 0) ? bm4[64] : 0.f;
  __syncthreads();

  const int ntiles = (E + 31) >> 5;
  for (int t = blockIdx.x; t < ntiles; t += gridDim.x){
    const int base = t << 5;
    // ---- stage X = [nf[src]|nf[dst]|ef] f32, rows 0..31, cols 0..143 ----
    {
      int row = wv*4 + quad;
      int e = base + row;
      int ec = e < E ? e : 0;
      int s = src[ec], d = dst[ec];
      *(f32x4*)(buf0 + row*B0S + nl*4)      = *(const f32x4*)(nf + (size_t)s*64 + nl*4);
      *(f32x4*)(buf0 + row*B0S + 64 + nl*4) = *(const f32x4*)(nf + (size_t)d*64 + nl*4);
      if (nl < 4) *(f32x4*)(buf0 + row*B0S + 128 + nl*4) = *(const f32x4*)(ef + (size_t)ec*16 + nl*4);
      if (nl == 5) dstIds[row] = (e < E) ? d : -1;
    }
    __syncthreads();

    // ---- L1: K=160 (144 real; k>=144 B is exact 0), buf0 -> buf1 ----
    f32x4 acc1 = {bi1, bi1, bi1, bi1};
    {
      const float* arow = buf0 + (m1*16 + nl)*B0S;
      #pragma unroll
      for (int kc = 0; kc < 5; ++kc){
        short8 ah, al; splitA(arow, kc*32 + quad*8, ah, al);
        acc1 = mfma3(ah, al, B1h[kc], B1l[kc], acc1);
      }
    }
    #pragma unroll
    for (int r = 0; r < 4; ++r)
      buf1[(m1*16 + quad*4 + r)*B1S + nb1*16 + nl] = lrelu(acc1[r]);
    __syncthreads();

    // ---- L2: K=64, dual n-block, buf1 -> buf0 cols 0..127 ----
    f32x4 acc2a = {bi2a, bi2a, bi2a, bi2a}, acc2b = {bi2b, bi2b, bi2b, bi2b};
    {
      const float* arow = buf1 + (m1*16 + nl)*B1S;
      #pragma unroll
      for (int kc = 0; kc < 2; ++kc){
        short8 ah, al; splitA(arow, kc*32 + quad*8, ah, al);
        acc2a = mfma3(ah, al, B2h[0][kc], B2l[0][kc], acc2a);
        acc2b = mfma3(ah, al, B2h[1][kc], B2l[1][kc], acc2b);
      }
    }
    #pragma unroll
    for (int r = 0; r < 4; ++r){
      buf0[(m1*16 + quad*4 + r)*B0S + nb1*16 + nl]      = lrelu(acc2a[r]);
      buf0[(m1*16 + quad*4 + r)*B0S + (nb1+4)*16 + nl]  = lrelu(acc2b[r]);
    }
    __syncthreads();

    // ---- L3: K=128, buf0 -> buf1 ----
    f32x4 acc3 = {bi3, bi3, bi3, bi3};
    {
      const float* arow = buf0 + (m1*16 + nl)*B0S;
      #pragma unroll
      for (int kc = 0; kc < 4; ++kc){
        short8 ah, al; splitA(arow, kc*32 + quad*8, ah, al);
        acc3 = mfma3(ah, al, B3h[kc], B3l[kc], acc3);
      }
    }
    #pragma unroll
    for (int r = 0; r < 4; ++r)
      buf1[(m1*16 + quad*4 + r)*B1S + nb1*16 + nl] = lrelu(acc3[r]);
    __syncthreads();

    // ---- L4: K=64, tileA (nb1) + tileB (col 64, waves with nb1==0) ----
    f32x4 acc4a = {bi4a, bi4a, bi4a, bi4a}, acc4b = {bi4b, bi4b, bi4b, bi4b};
    {
      const float* arow = buf1 + (m1*16 + nl)*B1S;
      #pragma unroll
      for (int kc = 0; kc < 2; ++kc){
        short8 ah, al; splitA(arow, kc*32 + quad*8, ah, al);
        acc4a = mfma3(ah, al, B4h[0][kc], B4l[0][kc], acc4a);
        if (nb1 == 0)
          acc4b = mfma3(ah, al, B4h[1][kc], B4l[1][kc], acc4b);
      }
    }
    if (nb1 == 0 && nl == 0){       // col 0 = gate logit, rows quad*4+r of m-block m1
      #pragma unroll
      for (int r = 0; r < 4; ++r)
        gates[m1*16 + quad*4 + r] = 1.f/(1.f + __expf(-acc4a[r]));
    }
    __syncthreads();

    // ---- scatter ----
    {
      int n = nb1*16 + nl;
      #pragma unroll
      for (int r = 0; r < 4; ++r){
        int row = m1*16 + quad*4 + r;
        int d = dstIds[row];
        if (d >= 0){
          float v = acc4a[r] * gates[row];
          if (n >= 1 && n <= 32)       atomicAdd(nf1 + (size_t)d*32 + (n-1), v);
          else if (n >= 33 && n <= 64) atomicMaxF(nf2 + (size_t)d*32 + (n-33), v);
        }
      }
      if (nb1 == 0 && nl == 0){      // tileB col 64 -> nf2 col 31
        #pragma unroll
        for (int r = 0; r < 4; ++r){
          int row = m1*16 + quad*4 + r;
          int d = dstIds[row];
          if (d >= 0) atomicMaxF(nf2 + (size_t)d*32 + 31, acc4b[r] * gates[row]);
        }
      }
    }
    __syncthreads();   // protect dstIds/gates/bufs before next staging
  }
}

#define C0S 132   // node buf0 stride: 132%32=4 -> 2-way; 528B %16=0

// -------- node kernel: 32 nodes per block-tile, 8 waves --------
// y=[nf|nf1|nf2fix]; 128->64->128->64->64 (last linear), f32 out
__global__ __launch_bounds__(512, 2) void node_mfma(
    const float* __restrict__ nf,
    const float* __restrict__ nf1, const float* __restrict__ nf2,
    const float* __restrict__ Wr1, const float* __restrict__ br1,
    const float* __restrict__ Wr2, const float* __restrict__ br2,
    const float* __restrict__ Wr3, const float* __restrict__ br3,
    const float* __restrict__ Wr4, const float* __restrict__ br4,
    float* __restrict__ out, int N)
{
  __shared__ float buf0[32*C0S];
  __shared__ float buf1[32*B1S];

  zero_f(buf0, 32*C0S);
  zero_f(buf1, 32*B1S);

  const int lane = threadIdx.x & 63, wv = threadIdx.x >> 6;
  const int nl = lane & 15, quad = lane >> 4;
  const int m = wv >> 2, nb = wv & 3;

  short8 B1h[4], B1l[4];
  #pragma unroll
  for (int kc = 0; kc < 4; ++kc) gatherB(Wr1, 128, 64,  kc*32 + quad*8, nb*16 + nl, B1h[kc], B1l[kc]);
  short8 B2h[2][2], B2l[2][2];
  #pragma unroll
  for (int i = 0; i < 2; ++i)
    #pragma unroll
    for (int kc = 0; kc < 2; ++kc) gatherB(Wr2, 64, 128, kc*32 + quad*8, (nb + i*4)*16 + nl, B2h[i][kc], B2l[i][kc]);
  short8 B3h[4], B3l[4];
  #pragma unroll
  for (int kc = 0; kc < 4; ++kc) gatherB(Wr3, 128, 64,  kc*32 + quad*8, nb*16 + nl, B3h[kc], B3l[kc]);
  short8 B4h[2], B4l[2];
  #pragma unroll
  for (int kc = 0; kc < 2; ++kc) gatherB(Wr4, 64, 64,   kc*32 + quad*8, nb*16 + nl, B4h[kc], B4l[kc]);

  const float bi1  = br1[nb*16 + nl];
  const float bi2a = br2[nb*16 + nl], bi2b = br2[(nb+4)*16 + nl];
  const float bi3  = br3[nb*16 + nl];
  const float bi4  = br4[nb*16 + nl];
  __syncthreads();

  const int ntiles = (N + 31) >> 5;
  for (int t = blockIdx.x; t < ntiles; t += gridDim.x){
    const int base = t << 5;
    // ---- stage y ----
    {
      int row = wv*4 + quad;
      int n = base + row;
      int nc = n < N ? n : 0;
      *(f32x4*)(buf0 + row*C0S + nl*4) = *(const f32x4*)(nf + (size_t)nc*64 + nl*4);
      if (nl < 8){
        *(f32x4*)(buf0 + row*C0S + 64 + nl*4) = *(const f32x4*)(nf1 + (size_t)nc*32 + nl*4);
      } else {
        f32x4 v = *(const f32x4*)(nf2 + (size_t)nc*32 + (nl-8)*4);
        #pragma unroll
        for (int j = 0; j < 4; ++j) if (!(v[j] >= -3.0e38f)) v[j] = 0.f;  // -inf/NaN -> 0
        *(f32x4*)(buf0 + row*C0S + 96 + (nl-8)*4) = v;
      }
    }
    __syncthreads();

    // L1: K=128
    f32x4 a1 = {bi1, bi1, bi1, bi1};
    {
      const float* arow = buf0 + (m*16 + nl)*C0S;
      #pragma unroll
      for (int kc = 0; kc < 4; ++kc){
        short8 ah, al; splitA(arow, kc*32 + quad*8, ah, al);
        a1 = mfma3(ah, al, B1h[kc], B1l[kc], a1);
      }
    }
    #pragma unroll
    for (int r = 0; r < 4; ++r)
      buf1[(m*16 + quad*4 + r)*B1S + nb*16 + nl] = lrelu(a1[r]);
    __syncthreads();

    // L2: K=64, dual nb
    f32x4 a2a = {bi2a, bi2a, bi2a, bi2a}, a2b = {bi2b, bi2b, bi2b, bi2b};
    {
      const float* arow = buf1 + (m*16 + nl)*B1S;
      #pragma unroll
      for (int kc = 0; kc < 2; ++kc){
        short8 ah, al; splitA(arow, kc*32 + quad*8, ah, al);
        a2a = mfma3(ah, al, B2h[0][kc], B2l[0][kc], a2a);
        a2b = mfma3(ah, al, B2h[1][kc], B2l[1][kc], a2b);
      }
    }
    #pragma unroll
    for (int r = 0; r < 4; ++r){
      buf0[(m*16 + quad*4 + r)*C0S + nb*16 + nl]     = lrelu(a2a[r]);
      buf0[(m*16 + quad*4 + r)*C0S + (nb+4)*16 + nl] = lrelu(a2b[r]);
    }
    __syncthreads();

    // L3: K=128
    f32x4 a3 = {bi3, bi3, bi3, bi3};
    {
      const float* arow = buf0 + (m*16 + nl)*C0S;
      #pragma unroll
      for (int kc = 0; kc < 4; ++kc){
        short8 ah, al; splitA(arow, kc*32 + quad*8, ah, al);
        a3 = mfma3(ah, al, B3h[kc], B3l[kc], a3);
      }
    }
    #pragma unroll
    for (int r = 0; r < 4; ++r)
      buf1[(m*16 + quad*4 + r)*B1S + nb*16 + nl] = lrelu(a3[r]);
    __syncthreads();

    // L4: K=64, linear, direct f32 store
    f32x4 a4 = {bi4, bi4, bi4, bi4};
    {
      const float* arow = buf1 + (m*16 + nl)*B1S;
      #pragma unroll
      for (int kc = 0; kc < 2; ++kc){
        short8 ah, al; splitA(arow, kc*32 + quad*8, ah, al);
        a4 = mfma3(ah, al, B4h[kc], B4l[kc], a4);
      }
    }
    #pragma unroll
    for (int r = 0; r < 4; ++r){
      int n = base + m*16 + quad*4 + r;
      if (n < N) out[(size_t)n*64 + nb*16 + nl] = a4[r];
    }
    // no end barrier needed: next stage writes buf0 only; stage barrier orders buf1 reuse
  }
}

extern "C" void kernel_launch(void* const* d_in, const int* in_sizes, int n_in,
                              void* d_out, int out_size, void* d_ws, size_t ws_size,
                              hipStream_t stream) {
  const float* nf  = (const float*)d_in[0];
  const float* ef  = (const float*)d_in[1];
  const int*   src = (const int*)d_in[2];
  const int*   dst = (const int*)d_in[3];

  const int N = in_sizes[0] / 64;
  const int E = in_sizes[2];

  float* nf1 = (float*)d_ws;               // [N,32] segment-sum
  float* nf2 = nf1 + (size_t)N * 32;       // [N,32] segment-max

  init_ws<<<2048, 256, 0, stream>>>(nf1, nf2, N * 32);

  edge_mfma<<<1024, 512, 0, stream>>>(
      nf, ef, src, dst,
      (const float*)d_in[4],  (const float*)d_in[5],  (const float*)d_in[6],  (const float*)d_in[7],
      (const float*)d_in[8],  (const float*)d_in[9],  (const float*)d_in[10], (const float*)d_in[11],
      nf1, nf2, E);

  node_mfma<<<512, 512, 0, stream>>>(
      nf, nf1, nf2,
      (const float*)d_in[12], (const float*)d_in[13], (const float*)d_in[14], (const float*)d_in[15],
      (const float*)d_in[16], (const float*)d_in[17], (const float*)d_in[18], (const float*)d_in[19],
      (float*)d_out, N);
}